// Round 1
// baseline (6772.209 us; speedup 1.0000x reference)
//
#include <hip/hip_runtime.h>
#include <math.h>

// Problem constants
// G=128 graphs, S=32 steps, P=16 nodes, D=768, C=256, NH=4 heads, OUT=7
// NR = G*P = 2048 rows in all per-step matrices.
#define NG 128
#define NS 32
#define NP 16
#define ND 768
#define NC 256
#define NHD 4
#define NOUT 7
#define NR 2048

// ---------------------------------------------------------------------------
// Generic fp32 tiled GEMM: C[M,N] = A[M,K] @ B[K,N] (+bias, +optional relu)
// A rows at A + row*lda (lda in floats, allows strided row gather for spk).
// Requires: M%64==0 handled via grid (M in {2048,128}), N%64==0, K%16==0,
// all true for every call site here. 64x64 tile, 256 thr, 4x4 per thread.
// ---------------------------------------------------------------------------
__global__ __launch_bounds__(256) void gemm_kernel(
    const float* __restrict__ A, const float* __restrict__ B,
    float* __restrict__ Cout, int M, int N, int K, int lda,
    const float* __restrict__ bias, int act)
{
    (void)M;
    __shared__ float As[16][68];
    __shared__ float Bs[16][68];
    const int tid = threadIdx.x;
    const int tx = tid & 15;
    const int ty = tid >> 4;
    const int row0 = blockIdx.y * 64;
    const int col0 = blockIdx.x * 64;
    float acc[4][4] = {};

    for (int kk = 0; kk < K; kk += 16) {
        // A tile: 64 rows x 16 k, float4 per thread (4 consecutive k)
        {
            const int r = tid >> 2;
            const int kq = (tid & 3) << 2;
            const float4 av = *(const float4*)(A + (size_t)(row0 + r) * lda + kk + kq);
            As[kq + 0][r] = av.x; As[kq + 1][r] = av.y;
            As[kq + 2][r] = av.z; As[kq + 3][r] = av.w;
        }
        // B tile: 16 k x 64 cols, float4 per thread (4 consecutive cols)
        {
            const int kr = tid >> 4;
            const int cq = (tid & 15) << 2;
            const float4 bv = *(const float4*)(B + (size_t)(kk + kr) * N + col0 + cq);
            *(float4*)&Bs[kr][cq] = bv;
        }
        __syncthreads();
#pragma unroll
        for (int k = 0; k < 16; ++k) {
            const float4 a4 = *(const float4*)&As[k][ty << 2];
            const float4 b4 = *(const float4*)&Bs[k][tx << 2];
            const float a[4] = {a4.x, a4.y, a4.z, a4.w};
            const float b[4] = {b4.x, b4.y, b4.z, b4.w};
#pragma unroll
            for (int i = 0; i < 4; ++i)
#pragma unroll
                for (int j = 0; j < 4; ++j)
                    acc[i][j] += a[i] * b[j];
        }
        __syncthreads();
    }
#pragma unroll
    for (int i = 0; i < 4; ++i) {
        const int r = row0 + (ty << 2) + i;
#pragma unroll
        for (int j = 0; j < 4; ++j) {
            const int c = col0 + (tx << 2) + j;
            float v = acc[i][j];
            if (bias) v += bias[c];
            if (act == 1) v = fmaxf(v, 0.f);
            Cout[(size_t)r * N + c] = v;
        }
    }
}

// ---------------------------------------------------------------------------
// Small helpers
// ---------------------------------------------------------------------------
__global__ __launch_bounds__(256) void zero_kernel(float* p, int n) {
    int i = blockIdx.x * 256 + threadIdx.x;
    if (i < n) p[i] = 0.f;
}

// x[G,S,P,D] -> xbuf[NR, D] taking s=0 slice
__global__ __launch_bounds__(256) void copyx0_kernel(const float* __restrict__ x,
                                                     float* __restrict__ xb) {
    const int n = blockIdx.x;           // 0..2047
    const int g = n >> 4, p = n & 15;
    const float* src = x + ((size_t)(g * NS * NP) + p) * ND; // (g*S+0)*P + p
    float* dst = xb + (size_t)n * ND;
    for (int d = threadIdx.x; d < ND; d += 256) dst[d] = src[d];
}

// in[R, Ccol] -> out[Ccol, R]
__global__ __launch_bounds__(256) void transpose_kernel(const float* __restrict__ in,
                                                        float* __restrict__ outp,
                                                        int R, int Ccol) {
    int idx = blockIdx.x * 256 + threadIdx.x;
    if (idx >= R * Ccol) return;
    int r = idx / Ccol, c = idx - r * Ccol;
    outp[(size_t)c * R + r] = in[idx];
}

// spWcT[k, o] = sp_W[o, k] + sp_W[o, k+768]  (combined speaker concat weight, transposed)
__global__ __launch_bounds__(256) void spwc_kernel(const float* __restrict__ spW,
                                                   float* __restrict__ outp) {
    int idx = blockIdx.x * 256 + threadIdx.x; // < 768*768
    if (idx >= ND * ND) return;
    int o = idx / ND, k = idx - o * ND;
    outp[(size_t)k * ND + o] = spW[(size_t)o * (2 * ND) + k] + spW[(size_t)o * (2 * ND) + ND + k];
}

__device__ __forceinline__ float sigf(float v) { return 1.f / (1.f + expf(-v)); }

// gi = m_prev@WihT + bih (in gi), gh = h@WhhT + bhh (in gh); h updated in place
__global__ __launch_bounds__(256) void gru1_kernel(const float* __restrict__ gi,
                                                   const float* __restrict__ gh,
                                                   float* __restrict__ h) {
    const int idx = blockIdx.x * 256 + threadIdx.x; // < NR*NC
    const int n = idx >> 8, c = idx & 255;
    const size_t b = (size_t)n * (3 * NC);
    const float r = sigf(gi[b + c] + gh[b + c]);
    const float z = sigf(gi[b + NC + c] + gh[b + NC + c]);
    const float nn = tanhf(gi[b + 2 * NC + c] + r * gh[b + 2 * NC + c]);
    h[idx] = (1.f - z) * nn + z * h[idx];
}

// zero-input GRU step: gi == bih
__global__ __launch_bounds__(256) void gru2_kernel(const float* __restrict__ gh,
                                                   const float* __restrict__ bih,
                                                   const float* __restrict__ h,
                                                   float* __restrict__ hn) {
    const int idx = blockIdx.x * 256 + threadIdx.x;
    const int n = idx >> 8, c = idx & 255;
    const size_t b = (size_t)n * (3 * NC);
    const float r = sigf(bih[c] + gh[b + c]);
    const float z = sigf(bih[NC + c] + gh[b + NC + c]);
    const float nn = tanhf(bih[2 * NC + c] + r * gh[b + 2 * NC + c]);
    hn[idx] = (1.f - z) * nn + z * h[idx];
}

// x_new: row p==0 of each graph replaced by spk
__global__ __launch_bounds__(256) void xnew_kernel(const float* __restrict__ pooled,
                                                   const float* __restrict__ spk,
                                                   float* __restrict__ xnew) {
    const int idx = blockIdx.x * 256 + threadIdx.x; // < NR*ND
    const int n = idx / ND;
    const int d = idx - n * ND;
    const int p = n & 15, g = n >> 4;
    xnew[idx] = (p == 0) ? spk[(size_t)g * ND + d] : pooled[idx];
}

// es/ed: per (n, head) dot of h fragment with att vectors. 1 wave per head.
__global__ __launch_bounds__(256) void esed_kernel(const float* __restrict__ hbuf,
                                                   const float* __restrict__ att_src,
                                                   const float* __restrict__ att_dst,
                                                   float* __restrict__ esed) {
    const int n = blockIdx.x;
    const int tid = threadIdx.x;
    const int hd = tid >> 6, lane = tid & 63;
    const float* row = hbuf + (size_t)n * (NHD * NC) + hd * NC;
    float s1 = 0.f, s2 = 0.f;
    for (int c = lane; c < NC; c += 64) {
        const float v = row[c];
        s1 += v * att_src[hd * NC + c];
        s2 += v * att_dst[hd * NC + c];
    }
    for (int off = 32; off; off >>= 1) {
        s1 += __shfl_down(s1, off);
        s2 += __shfl_down(s2, off);
    }
    if (lane == 0) {
        esed[n * NHD + hd] = s1;
        esed[NR * NHD + n * NHD + hd] = s2;
    }
}

// GAT edge softmax (star graph: speaker->t edge + self loop) + head mean + bias
__global__ __launch_bounds__(256) void gat_combine_kernel(const float* __restrict__ hbuf,
                                                          const float* __restrict__ esed,
                                                          const float* __restrict__ gat_b,
                                                          float* __restrict__ mout) {
    const int n = blockIdx.x;
    const int c = threadIdx.x;
    const int p = n & 15;
    const int n0 = n - p;
    const float* es = esed;
    const float* ed = esed + NR * NHD;
    float acc = 0.f;
#pragma unroll
    for (int hd = 0; hd < NHD; ++hd) {
        const float es0 = es[n0 * NHD + hd];
        const float esn = es[n * NHD + hd];
        const float edn = ed[n * NHD + hd];
        float e1 = es0 + edn; e1 = e1 > 0.f ? e1 : 0.2f * e1;  // speaker->t
        float e2 = esn + edn; e2 = e2 > 0.f ? e2 : 0.2f * e2;  // self loop
        const float mx = fmaxf(e1, e2);
        const float w0 = expf(e1 - mx), w1 = expf(e2 - mx);
        const float inv = 1.f / (w0 + w1);
        acc += (w0 * inv) * hbuf[(size_t)n0 * (NHD * NC) + hd * NC + c]
             + (w1 * inv) * hbuf[(size_t)n  * (NHD * NC) + hd * NC + c];
    }
    mout[(size_t)n * NC + c] = acc * 0.25f + gat_b[c];
}

// GlobalAttention pool over P + classifier, for one step s. 1 block per graph.
__global__ __launch_bounds__(256) void pool_cls_kernel(const float* __restrict__ m,
                                                       const float* __restrict__ att_W,
                                                       const float* __restrict__ att_b,
                                                       const float* __restrict__ cls_W,
                                                       const float* __restrict__ cls_b,
                                                       float* __restrict__ out, int s) {
    const int g = blockIdx.x;
    const int tid = threadIdx.x;
    const int lane = tid & 63, w = tid >> 6;
    __shared__ float tval[NP];
    __shared__ float pooled_s[NC];
    // gate pre-activations: 4 waves x 4 nodes each
    for (int pi = 0; pi < 4; ++pi) {
        const int p = w * 4 + pi;
        const float* row = m + (size_t)(g * NP + p) * NC;
        float s1 = 0.f;
        for (int c = lane; c < NC; c += 64) s1 += row[c] * att_W[c];
        for (int off = 32; off; off >>= 1) s1 += __shfl_down(s1, off);
        if (lane == 0) tval[p] = s1 + att_b[0];
    }
    __syncthreads();
    float gate[NP];
    float mx = -1e30f;
    for (int p = 0; p < NP; ++p) mx = fmaxf(mx, tval[p]);
    float sum = 0.f;
    for (int p = 0; p < NP; ++p) { gate[p] = expf(tval[p] - mx); sum += gate[p]; }
    const float inv = 1.f / sum;
    float pc = 0.f;
    for (int p = 0; p < NP; ++p)
        pc += gate[p] * inv * m[(size_t)(g * NP + p) * NC + tid];
    pooled_s[tid] = pc;
    __syncthreads();
    if (tid < NOUT) {
        float acc = cls_b[tid];
        for (int c = 0; c < NC; ++c) acc += pooled_s[c] * cls_W[tid * NC + c];
        out[(size_t)(g * NS + s) * NOUT + tid] = acc;  // graph-major [G*S, 1, OUT]
    }
}

// ---------------------------------------------------------------------------
extern "C" void kernel_launch(void* const* d_in, const int* in_sizes, int n_in,
                              void* d_out, int out_size, void* d_ws, size_t ws_size,
                              hipStream_t stream) {
    (void)in_sizes; (void)n_in; (void)out_size; (void)ws_size;
    const float* x       = (const float*)d_in[0];
    const float* gat_W   = (const float*)d_in[1];
    const float* att_src = (const float*)d_in[2];
    const float* att_dst = (const float*)d_in[3];
    const float* gat_b   = (const float*)d_in[4];
    const float* gru_Wih = (const float*)d_in[5];
    const float* gru_Whh = (const float*)d_in[6];
    const float* gru_bih = (const float*)d_in[7];
    const float* gru_bhh = (const float*)d_in[8];
    const float* up_W    = (const float*)d_in[9];
    const float* up_b    = (const float*)d_in[10];
    const float* sp_W    = (const float*)d_in[11];
    const float* sp_b    = (const float*)d_in[12];
    const float* att_W   = (const float*)d_in[13];
    const float* att_b   = (const float*)d_in[14];
    const float* cls_W   = (const float*)d_in[15];
    const float* cls_b   = (const float*)d_in[16];
    float* out = (float*)d_out;

    // Workspace layout (floats); total ~11.8M floats = 47.1 MB
    float* ws     = (float*)d_ws;
    float* xnew   = ws;                        // NR*ND
    float* gi     = xnew + (size_t)NR * ND;    // NR*768
    float* gh     = gi + (size_t)NR * ND;      // NR*768
    float* pooled = gh + (size_t)NR * ND;      // NR*ND
    float* hbuf   = pooled + (size_t)NR * ND;  // NR*1024
    float* m_a    = hbuf + (size_t)NR * (NHD * NC); // NR*NC
    float* m_b    = m_a + (size_t)NR * NC;
    float* h_run  = m_b + (size_t)NR * NC;
    float* h_nxt  = h_run + (size_t)NR * NC;
    float* spkbuf = h_nxt + (size_t)NR * NC;   // NG*ND
    float* esed   = spkbuf + (size_t)NG * ND;  // NR*NHD*2
    float* WihT   = esed + (size_t)NR * NHD * 2; // NC x 3NC^T => 256*768
    float* WhhT   = WihT + (size_t)NC * (3 * NC);
    float* upWT   = WhhT + (size_t)NC * (3 * NC);
    float* spWcT  = upWT + (size_t)NC * ND;    // 768*768

    // init + weight prep (every call; ws is re-poisoned between calls)
    zero_kernel<<<(NR * NC + 255) / 256, 256, 0, stream>>>(h_run, NR * NC);
    copyx0_kernel<<<NR, 256, 0, stream>>>(x, xnew);
    transpose_kernel<<<(3 * NC * NC + 255) / 256, 256, 0, stream>>>(gru_Wih, WihT, 3 * NC, NC);
    transpose_kernel<<<(3 * NC * NC + 255) / 256, 256, 0, stream>>>(gru_Whh, WhhT, 3 * NC, NC);
    transpose_kernel<<<(ND * NC + 255) / 256, 256, 0, stream>>>(up_W, upWT, ND, NC);
    spwc_kernel<<<(ND * ND + 255) / 256, 256, 0, stream>>>(sp_W, spWcT);

    // m0 = GAT(x[:,0])
    gemm_kernel<<<dim3(16, 32), 256, 0, stream>>>(xnew, gat_W, hbuf, NR, NHD * NC, ND, ND, nullptr, 0);
    esed_kernel<<<NR, 256, 0, stream>>>(hbuf, att_src, att_dst, esed);
    gat_combine_kernel<<<NR, 256, 0, stream>>>(hbuf, esed, gat_b, m_a);
    pool_cls_kernel<<<NG, 256, 0, stream>>>(m_a, att_W, att_b, cls_W, cls_b, out, 0);

    float* mp = m_a;
    float* mc = m_b;
    for (int j = 1; j < NS; ++j) {
        // GRU over memory input
        gemm_kernel<<<dim3(12, 32), 256, 0, stream>>>(mp, WihT, gi, NR, 3 * NC, NC, NC, gru_bih, 0);
        gemm_kernel<<<dim3(12, 32), 256, 0, stream>>>(h_run, WhhT, gh, NR, 3 * NC, NC, NC, gru_bhh, 0);
        gru1_kernel<<<NR, 256, 0, stream>>>(gi, gh, h_run);
        // zero-input GRU step
        gemm_kernel<<<dim3(12, 32), 256, 0, stream>>>(h_run, WhhT, gh, NR, 3 * NC, NC, NC, gru_bhh, 0);
        gru2_kernel<<<NR, 256, 0, stream>>>(gh, gru_bih, h_run, h_nxt);
        // up-projection to D
        gemm_kernel<<<dim3(12, 32), 256, 0, stream>>>(h_nxt, upWT, pooled, NR, ND, NC, NC, up_b, 0);
        // speaker projection (rows p==0, strided lda = P*D), combined concat weight, relu
        gemm_kernel<<<dim3(12, 2), 256, 0, stream>>>(pooled, spWcT, spkbuf, NG, ND, ND, NP * ND, sp_b, 1);
        xnew_kernel<<<(NR * ND + 255) / 256, 256, 0, stream>>>(pooled, spkbuf, xnew);
        // GAT
        gemm_kernel<<<dim3(16, 32), 256, 0, stream>>>(xnew, gat_W, hbuf, NR, NHD * NC, ND, ND, nullptr, 0);
        esed_kernel<<<NR, 256, 0, stream>>>(hbuf, att_src, att_dst, esed);
        gat_combine_kernel<<<NR, 256, 0, stream>>>(hbuf, esed, gat_b, mc);
        // fused pool+classify for this step (mem[S] never materialized)
        pool_cls_kernel<<<NG, 256, 0, stream>>>(mc, att_W, att_b, cls_W, cls_b, out, j);
        float* t = mp; mp = mc; mc = t;
    }
}

// Round 2
// 2644.020 us; speedup vs baseline: 2.5613x; 2.5613x over previous
//
#include <hip/hip_runtime.h>
#include <math.h>

// G=128, S=32, P=16, D=768, C=256, NH=4, OUT=7; NR = G*P = 2048
#define NG 128
#define NS 32
#define NP 16
#define ND 768
#define NC 256
#define NHD 4
#define NOUT 7
#define NR 2048

typedef unsigned short ushortT;
typedef short bf16x8 __attribute__((ext_vector_type(8)));
typedef float f32x4 __attribute__((ext_vector_type(4)));

__device__ __forceinline__ ushortT f2b(float f) {
    union { float f; unsigned u; } v; v.f = f;
    unsigned r = (v.u + 0x7FFF + ((v.u >> 16) & 1)) >> 16;
    return (ushortT)r;
}
__device__ __forceinline__ float sigf(float v) { return 1.f / (1.f + expf(-v)); }

#define MFMA16(a, b, c) __builtin_amdgcn_mfma_f32_16x16x32_bf16((a), (b), (c), 0, 0, 0)

// ---------------------------------------------------------------------------
// Generic bf16 MFMA GEMM, 64x64 tile, 256 thr (4 waves, each 32x32 = 2x2 frags)
// A [M,K] bf16 row-major; Bt [N,K] bf16 (B transposed); out fp32 and/or bf16.
// Asub: if non-null, rows with (row&15)==0 come from Asub[(row>>4)*K] (GAT
// speaker substitution). grid = (N/64, M/64).
// ---------------------------------------------------------------------------
__global__ __launch_bounds__(256) void bgemm_kernel(
    const ushortT* __restrict__ A, const ushortT* __restrict__ Asub,
    const ushortT* __restrict__ Bt, const float* __restrict__ bias,
    float* __restrict__ outF, ushortT* __restrict__ outH,
    int N, int K, int act)
{
    __shared__ short As[64 * 40];
    __shared__ short Bs[64 * 40];
    const int tid = threadIdx.x;
    const int lane = tid & 63, wid = tid >> 6;
    const int quad = lane >> 4, l15 = lane & 15;
    const int row0 = blockIdx.y * 64, col0 = blockIdx.x * 64;
    const int mh = (wid & 1) * 32, nh = (wid >> 1) * 32;
    const int sr = tid >> 2, skq = (tid & 3) * 8;
    const int grow_s = row0 + sr;
    const ushortT* aptr = (Asub && ((grow_s & 15) == 0))
        ? Asub + (size_t)(grow_s >> 4) * K : A + (size_t)grow_s * K;
    const ushortT* bptr = Bt + (size_t)(col0 + sr) * K;

    f32x4 acc[2][2];
    for (int i = 0; i < 2; ++i)
        for (int j = 0; j < 2; ++j) acc[i][j] = (f32x4){0.f, 0.f, 0.f, 0.f};

    for (int kk = 0; kk < K; kk += 32) {
        __syncthreads();
        *(uint4*)&As[sr * 40 + skq] = *(const uint4*)(aptr + kk + skq);
        *(uint4*)&Bs[sr * 40 + skq] = *(const uint4*)(bptr + kk + skq);
        __syncthreads();
        bf16x8 af0 = *(const bf16x8*)&As[(mh + l15) * 40 + quad * 8];
        bf16x8 af1 = *(const bf16x8*)&As[(mh + 16 + l15) * 40 + quad * 8];
        bf16x8 bf0 = *(const bf16x8*)&Bs[(nh + l15) * 40 + quad * 8];
        bf16x8 bf1 = *(const bf16x8*)&Bs[(nh + 16 + l15) * 40 + quad * 8];
        acc[0][0] = MFMA16(af0, bf0, acc[0][0]);
        acc[0][1] = MFMA16(af0, bf1, acc[0][1]);
        acc[1][0] = MFMA16(af1, bf0, acc[1][0]);
        acc[1][1] = MFMA16(af1, bf1, acc[1][1]);
    }
#pragma unroll
    for (int mt = 0; mt < 2; ++mt)
#pragma unroll
        for (int nt = 0; nt < 2; ++nt) {
            const int gc = col0 + nh + nt * 16 + l15;
            const float bv = bias ? bias[gc] : 0.f;
#pragma unroll
            for (int r = 0; r < 4; ++r) {
                const int gr = row0 + mh + mt * 16 + quad * 4 + r;
                float v = acc[mt][nt][r] + bv;
                if (act) v = fmaxf(v, 0.f);
                if (outF) outF[(size_t)gr * N + gc] = v;
                if (outH) outH[(size_t)gr * N + gc] = f2b(v);
            }
        }
}

// ---------------------------------------------------------------------------
// Fused GRU step 1: gi = m@Wih^T, gh = h@Whh^T, gate math, h updated in place.
// Block: 32 rows x 64 hidden cols; 6 accumulator groups (gi/gh x r/z/n) via
// gate-offset B rows. grid = (256/64, 2048/32) = (4, 64).
// ---------------------------------------------------------------------------
__global__ __launch_bounds__(256) void gru1_mfma_kernel(
    const ushortT* __restrict__ mB, const ushortT* __restrict__ hB,
    const ushortT* __restrict__ WihB, const ushortT* __restrict__ WhhB,
    const float* __restrict__ bih, const float* __restrict__ bhh,
    float* __restrict__ hF, ushortT* __restrict__ hBout)
{
    __shared__ short As[2 * 32 * 264];   // [mat][row][264] (256 k + pad 8)
    __shared__ short Bs[384 * 40];       // [w*192 + gt*64 + nloc][32 k + pad]
    const int tid = threadIdx.x;
    const int lane = tid & 63, wid = tid >> 6;
    const int quad = lane >> 4, l15 = lane & 15;
    const int row0 = blockIdx.y * 32;
    const int n0 = blockIdx.x * 64;
    const int mt = wid & 1, nhh = (wid >> 1) * 32;

    for (int c = tid; c < 2048; c += 256) {
        const int mat = c >> 10, r2 = c & 1023, row = r2 >> 5, kc = (r2 & 31) * 8;
        const ushortT* src = (mat ? hB : mB) + (size_t)(row0 + row) * NC + kc;
        *(uint4*)&As[mat * 8448 + row * 264 + kc] = *(const uint4*)src;
    }
    f32x4 acc[2][3][2];
    for (int w = 0; w < 2; ++w)
        for (int g = 0; g < 3; ++g)
            for (int n = 0; n < 2; ++n) acc[w][g][n] = (f32x4){0.f, 0.f, 0.f, 0.f};

    for (int kk = 0; kk < 256; kk += 32) {
        __syncthreads();
        for (int c = tid; c < 1536; c += 256) {
            const int j = c >> 2, kq = (c & 3) * 8;
            const int w = j / 192, j2 = j - w * 192, gt = j2 >> 6, nloc = j2 & 63;
            const ushortT* src = (w ? WhhB : WihB) +
                (size_t)(gt * 256 + n0 + nloc) * NC + kk + kq;
            *(uint4*)&Bs[j * 40 + kq] = *(const uint4*)src;
        }
        __syncthreads();
        bf16x8 af0 = *(const bf16x8*)&As[(mt * 16 + l15) * 264 + kk + quad * 8];
        bf16x8 af1 = *(const bf16x8*)&As[8448 + (mt * 16 + l15) * 264 + kk + quad * 8];
#pragma unroll
        for (int gt = 0; gt < 3; ++gt)
#pragma unroll
            for (int nt = 0; nt < 2; ++nt) {
                const int jb = gt * 64 + nhh + nt * 16 + l15;
                bf16x8 b0 = *(const bf16x8*)&Bs[jb * 40 + quad * 8];
                bf16x8 b1 = *(const bf16x8*)&Bs[(192 + jb) * 40 + quad * 8];
                acc[0][gt][nt] = MFMA16(af0, b0, acc[0][gt][nt]);
                acc[1][gt][nt] = MFMA16(af1, b1, acc[1][gt][nt]);
            }
    }
#pragma unroll
    for (int nt = 0; nt < 2; ++nt) {
        const int c = n0 + nhh + nt * 16 + l15;
        const float br = bih[c], bz = bih[256 + c], bn = bih[512 + c];
        const float cr = bhh[c], cz = bhh[256 + c], cn = bhh[512 + c];
#pragma unroll
        for (int r = 0; r < 4; ++r) {
            const int grow = row0 + mt * 16 + quad * 4 + r;
            const size_t idx = (size_t)grow * NC + c;
            const float hold = hF[idx];
            const float rg = sigf(acc[0][0][nt][r] + br + acc[1][0][nt][r] + cr);
            const float zg = sigf(acc[0][1][nt][r] + bz + acc[1][1][nt][r] + cz);
            const float ng = tanhf(acc[0][2][nt][r] + bn + rg * (acc[1][2][nt][r] + cn));
            const float hn = (1.f - zg) * ng + zg * hold;
            hF[idx] = hn;
            hBout[idx] = f2b(hn);
        }
    }
}

// ---------------------------------------------------------------------------
// Fused GRU step 2 (zero input): gh = h@Whh^T, gi = bih; h_nxt out (bf16),
// plus compact speaker rows h0c. grid = (4, 64).
// ---------------------------------------------------------------------------
__global__ __launch_bounds__(256) void gru2_mfma_kernel(
    const ushortT* __restrict__ hB, const ushortT* __restrict__ WhhB,
    const float* __restrict__ bih, const float* __restrict__ bhh,
    const float* __restrict__ hF, ushortT* __restrict__ hnB,
    ushortT* __restrict__ h0c)
{
    __shared__ short As[32 * 264];
    __shared__ short Bs[192 * 40];
    const int tid = threadIdx.x;
    const int lane = tid & 63, wid = tid >> 6;
    const int quad = lane >> 4, l15 = lane & 15;
    const int row0 = blockIdx.y * 32;
    const int n0 = blockIdx.x * 64;
    const int mt = wid & 1, nhh = (wid >> 1) * 32;

    for (int c = tid; c < 1024; c += 256) {
        const int row = c >> 5, kc = (c & 31) * 8;
        *(uint4*)&As[row * 264 + kc] =
            *(const uint4*)(hB + (size_t)(row0 + row) * NC + kc);
    }
    f32x4 acc[3][2];
    for (int g = 0; g < 3; ++g)
        for (int n = 0; n < 2; ++n) acc[g][n] = (f32x4){0.f, 0.f, 0.f, 0.f};

    for (int kk = 0; kk < 256; kk += 32) {
        __syncthreads();
        for (int c = tid; c < 768; c += 256) {
            const int j = c >> 2, kq = (c & 3) * 8;
            const int gt = j >> 6, nloc = j & 63;
            *(uint4*)&Bs[j * 40 + kq] =
                *(const uint4*)(WhhB + (size_t)(gt * 256 + n0 + nloc) * NC + kk + kq);
        }
        __syncthreads();
        bf16x8 af = *(const bf16x8*)&As[(mt * 16 + l15) * 264 + kk + quad * 8];
#pragma unroll
        for (int gt = 0; gt < 3; ++gt)
#pragma unroll
            for (int nt = 0; nt < 2; ++nt) {
                const int jb = gt * 64 + nhh + nt * 16 + l15;
                bf16x8 b = *(const bf16x8*)&Bs[jb * 40 + quad * 8];
                acc[gt][nt] = MFMA16(af, b, acc[gt][nt]);
            }
    }
#pragma unroll
    for (int nt = 0; nt < 2; ++nt) {
        const int c = n0 + nhh + nt * 16 + l15;
        const float br = bih[c], bz = bih[256 + c], bn = bih[512 + c];
        const float cr = bhh[c], cz = bhh[256 + c], cn = bhh[512 + c];
#pragma unroll
        for (int r = 0; r < 4; ++r) {
            const int grow = row0 + mt * 16 + quad * 4 + r;
            const size_t idx = (size_t)grow * NC + c;
            const float rg = sigf(br + acc[0][nt][r] + cr);
            const float zg = sigf(bz + acc[1][nt][r] + cz);
            const float ng = tanhf(bn + rg * (acc[2][nt][r] + cn));
            const float hv = (1.f - zg) * ng + zg * hF[idx];
            const ushortT hb = f2b(hv);
            hnB[idx] = hb;
            if ((grow & 15) == 0) h0c[(size_t)(grow >> 4) * NC + c] = hb;
        }
    }
}

// ---------------------------------------------------------------------------
// Fused GAT-softmax + head-mean + GlobalAttention pool + classifier.
// One block per graph. hbuf fp32 [2048][1024].
// ---------------------------------------------------------------------------
__global__ __launch_bounds__(256) void fin_kernel(
    const float* __restrict__ hbuf, const float* __restrict__ att_src,
    const float* __restrict__ att_dst, const float* __restrict__ gat_b,
    const float* __restrict__ attW, const float* __restrict__ attb,
    const float* __restrict__ clsW, const float* __restrict__ clsb,
    ushortT* __restrict__ mB, float* __restrict__ outp, int s)
{
    const int g = blockIdx.x, tid = threadIdx.x;
    const int lane = tid & 63, wid = tid >> 6;
    __shared__ float es_s[16][4], ed_s[16][4];
    __shared__ float m_s[16][260];
    __shared__ float gate_s[16];
    __shared__ float pooled_s[256];
    const float* hb = hbuf + (size_t)g * NP * (NHD * NC);

    for (int pi = 0; pi < 4; ++pi) {
        const int p = wid * 4 + pi;
        const float* row = hb + p * (NHD * NC);
        float ss[4] = {0.f, 0.f, 0.f, 0.f}, sd[4] = {0.f, 0.f, 0.f, 0.f};
#pragma unroll
        for (int i = 0; i < 16; ++i) {
            const int col = lane + 64 * i;
            const float v = row[col];
            ss[i >> 2] += v * att_src[col];
            sd[i >> 2] += v * att_dst[col];
        }
        for (int off = 32; off; off >>= 1)
#pragma unroll
            for (int h = 0; h < 4; ++h) {
                ss[h] += __shfl_down(ss[h], off);
                sd[h] += __shfl_down(sd[h], off);
            }
        if (lane == 0)
#pragma unroll
            for (int h = 0; h < 4; ++h) { es_s[p][h] = ss[h]; ed_s[p][h] = sd[h]; }
    }
    __syncthreads();
    {
        const int p = tid >> 4, cb = (tid & 15) * 16;
        float accv[16];
#pragma unroll
        for (int cj = 0; cj < 16; ++cj) accv[cj] = 0.f;
#pragma unroll
        for (int h = 0; h < 4; ++h) {
            float e1 = es_s[0][h] + ed_s[p][h]; e1 = e1 > 0.f ? e1 : 0.2f * e1;
            float e2 = es_s[p][h] + ed_s[p][h]; e2 = e2 > 0.f ? e2 : 0.2f * e2;
            const float mx = fmaxf(e1, e2);
            float w0 = expf(e1 - mx), w1 = expf(e2 - mx);
            const float inv = 1.f / (w0 + w1);
            w0 *= inv; w1 *= inv;
            const float* r0 = hb + h * NC + cb;
            const float* rp = hb + p * (NHD * NC) + h * NC + cb;
#pragma unroll
            for (int cj = 0; cj < 16; ++cj) accv[cj] += w0 * r0[cj] + w1 * rp[cj];
        }
#pragma unroll
        for (int cj = 0; cj < 16; ++cj) {
            const float v = accv[cj] * 0.25f + gat_b[cb + cj];
            m_s[p][cb + cj] = v;
            mB[(size_t)(g * NP + p) * NC + cb + cj] = f2b(v);
        }
    }
    __syncthreads();
    for (int pi = 0; pi < 4; ++pi) {
        const int p = wid * 4 + pi;
        float sg = 0.f;
#pragma unroll
        for (int i = 0; i < 4; ++i) { const int c = lane + 64 * i; sg += m_s[p][c] * attW[c]; }
        for (int off = 32; off; off >>= 1) sg += __shfl_down(sg, off);
        if (lane == 0) gate_s[p] = sg + attb[0];
    }
    __syncthreads();
    float mx = -1e30f;
#pragma unroll
    for (int p = 0; p < 16; ++p) mx = fmaxf(mx, gate_s[p]);
    float ge[16], ssum = 0.f;
#pragma unroll
    for (int p = 0; p < 16; ++p) { ge[p] = expf(gate_s[p] - mx); ssum += ge[p]; }
    const float inv = 1.f / ssum;
    {
        float pc = 0.f;
#pragma unroll
        for (int p = 0; p < 16; ++p) pc += ge[p] * m_s[p][tid];
        pooled_s[tid] = pc * inv;
    }
    __syncthreads();
    const int o = tid >> 5, l32 = tid & 31;
    if (o < NOUT) {
        float a = 0.f;
#pragma unroll
        for (int i = 0; i < 8; ++i) {
            const int c = l32 + 32 * i;
            a += pooled_s[c] * clsW[o * NC + c];
        }
        for (int off = 16; off; off >>= 1) a += __shfl_down(a, off);
        if (l32 == 0) outp[((size_t)g * NS + s) * NOUT + o] = a + clsb[o];
    }
}

// ---------------------------------------------------------------------------
// Prep kernels
// ---------------------------------------------------------------------------
__global__ __launch_bounds__(256) void cast_kernel(const float* __restrict__ a,
                                                   ushortT* __restrict__ b, int n) {
    const int i = blockIdx.x * 256 + threadIdx.x;
    if (i < n) b[i] = f2b(a[i]);
}
__global__ __launch_bounds__(256) void gatT_kernel(const float* __restrict__ gW,
                                                   ushortT* __restrict__ gB) {
    const int idx = blockIdx.x * 256 + threadIdx.x; // < 1024*768
    const int c = idx / ND, d = idx - c * ND;
    gB[idx] = f2b(gW[(size_t)d * (NHD * NC) + c]);
}
__global__ __launch_bounds__(256) void spwc_kernel(const float* __restrict__ spW,
                                                   float* __restrict__ o) {
    const int idx = blockIdx.x * 256 + threadIdx.x; // < 768*768
    const int r = idx / ND, d = idx - r * ND;
    o[idx] = spW[(size_t)r * (2 * ND) + d] + spW[(size_t)r * (2 * ND) + ND + d];
}
// WusB[o][c] = sum_d spWc[o][d] * upW[d][c]  (bf16 out, BT layout [768][256])
__global__ __launch_bounds__(256) void wus_kernel(const float* __restrict__ spWc,
                                                  const float* __restrict__ upW,
                                                  ushortT* __restrict__ WusB) {
    const int c = threadIdx.x;
    const int o0 = blockIdx.x * 16;
    float acc[16];
#pragma unroll
    for (int i = 0; i < 16; ++i) acc[i] = 0.f;
    for (int d = 0; d < ND; ++d) {
        const float u = upW[(size_t)d * NC + c];
#pragma unroll
        for (int i = 0; i < 16; ++i) acc[i] += spWc[(size_t)(o0 + i) * ND + d] * u;
    }
#pragma unroll
    for (int i = 0; i < 16; ++i) WusB[(size_t)(o0 + i) * NC + c] = f2b(acc[i]);
}
__global__ __launch_bounds__(256) void bus_kernel(const float* __restrict__ spWc,
                                                  const float* __restrict__ up_b,
                                                  const float* __restrict__ sp_b,
                                                  float* __restrict__ bus) {
    const int o = blockIdx.x * 256 + threadIdx.x;
    if (o >= ND) return;
    float a = sp_b[o];
    const float* sr = spWc + (size_t)o * ND;
    for (int d = 0; d < ND; ++d) a += sr[d] * up_b[d];
    bus[o] = a;
}
__global__ __launch_bounds__(256) void x0_kernel(const float* __restrict__ x,
                                                 ushortT* __restrict__ xb) {
    const int idx = blockIdx.x * 256 + threadIdx.x; // < 2048*768
    const int row = idx / ND, d = idx - row * ND;
    const int g = row >> 4, p = row & 15;
    xb[idx] = f2b(x[((size_t)g * (NS * NP) + p) * ND + d]);
}
__global__ __launch_bounds__(256) void zh_kernel(float* hF, ushortT* hB) {
    const int idx = blockIdx.x * 256 + threadIdx.x; // < 2048*256
    hF[idx] = 0.f;
    hB[idx] = 0;
}

// ---------------------------------------------------------------------------
extern "C" void kernel_launch(void* const* d_in, const int* in_sizes, int n_in,
                              void* d_out, int out_size, void* d_ws, size_t ws_size,
                              hipStream_t stream) {
    (void)in_sizes; (void)n_in; (void)out_size; (void)ws_size;
    const float* x       = (const float*)d_in[0];
    const float* gat_W   = (const float*)d_in[1];
    const float* att_src = (const float*)d_in[2];
    const float* att_dst = (const float*)d_in[3];
    const float* gat_b   = (const float*)d_in[4];
    const float* gru_Wih = (const float*)d_in[5];
    const float* gru_Whh = (const float*)d_in[6];
    const float* gru_bih = (const float*)d_in[7];
    const float* gru_bhh = (const float*)d_in[8];
    const float* up_W    = (const float*)d_in[9];
    const float* up_b    = (const float*)d_in[10];
    const float* sp_W    = (const float*)d_in[11];
    const float* sp_b    = (const float*)d_in[12];
    const float* att_W   = (const float*)d_in[13];
    const float* att_b   = (const float*)d_in[14];
    const float* cls_W   = (const float*)d_in[15];
    const float* cls_b   = (const float*)d_in[16];
    float* outp = (float*)d_out;

    char* w = (char*)d_ws;
    ushortT* xb    = (ushortT*)w; w += (size_t)NR * ND * 2;
    ushortT* WihB  = (ushortT*)w; w += (size_t)(3 * NC) * NC * 2;
    ushortT* WhhB  = (ushortT*)w; w += (size_t)(3 * NC) * NC * 2;
    ushortT* upWB  = (ushortT*)w; w += (size_t)ND * NC * 2;
    ushortT* gatB  = (ushortT*)w; w += (size_t)(NHD * NC) * ND * 2;
    ushortT* WusB  = (ushortT*)w; w += (size_t)ND * NC * 2;
    float*   spWc  = (float*)w;   w += (size_t)ND * ND * 4;
    float*   bus   = (float*)w;   w += (size_t)ND * 4;
    float*   hF    = (float*)w;   w += (size_t)NR * NC * 4;
    ushortT* hB    = (ushortT*)w; w += (size_t)NR * NC * 2;
    ushortT* hnB   = (ushortT*)w; w += (size_t)NR * NC * 2;
    ushortT* h0c   = (ushortT*)w; w += (size_t)NG * NC * 2;
    ushortT* poolB = (ushortT*)w; w += (size_t)NR * ND * 2;
    ushortT* spkB  = (ushortT*)w; w += (size_t)NG * ND * 2;
    float*   hbuf  = (float*)w;   w += (size_t)NR * (NHD * NC) * 4;
    ushortT* mB    = (ushortT*)w; w += (size_t)NR * NC * 2;

    // ---- prep (runs every call; ws re-poisoned between calls) ----
    cast_kernel<<<768, 256, 0, stream>>>(gru_Wih, WihB, 3 * NC * NC);
    cast_kernel<<<768, 256, 0, stream>>>(gru_Whh, WhhB, 3 * NC * NC);
    cast_kernel<<<768, 256, 0, stream>>>(up_W, upWB, ND * NC);
    gatT_kernel<<<(NHD * NC * ND) / 256, 256, 0, stream>>>(gat_W, gatB);
    spwc_kernel<<<(ND * ND) / 256, 256, 0, stream>>>(sp_W, spWc);
    wus_kernel<<<ND / 16, 256, 0, stream>>>(spWc, up_W, WusB);
    bus_kernel<<<3, 256, 0, stream>>>(spWc, up_b, sp_b, bus);
    x0_kernel<<<(NR * ND) / 256, 256, 0, stream>>>(x, xb);
    zh_kernel<<<(NR * NC) / 256, 256, 0, stream>>>(hF, hB);

    // ---- step 0: m0 = GAT(x0); pool+classify s=0 ----
    bgemm_kernel<<<dim3((NHD * NC) / 64, NR / 64), 256, 0, stream>>>(
        xb, nullptr, gatB, nullptr, hbuf, nullptr, NHD * NC, ND, 0);
    fin_kernel<<<NG, 256, 0, stream>>>(hbuf, att_src, att_dst, gat_b,
                                       att_W, att_b, cls_W, cls_b, mB, outp, 0);

    // ---- steps 1..31 ----
    for (int j = 1; j < NS; ++j) {
        gru1_mfma_kernel<<<dim3(NC / 64, NR / 32), 256, 0, stream>>>(
            mB, hB, WihB, WhhB, gru_bih, gru_bhh, hF, hB);
        gru2_mfma_kernel<<<dim3(NC / 64, NR / 32), 256, 0, stream>>>(
            hB, WhhB, gru_bih, gru_bhh, hF, hnB, h0c);
        bgemm_kernel<<<dim3(ND / 64, NR / 64), 256, 0, stream>>>(
            hnB, nullptr, upWB, up_b, nullptr, poolB, ND, NC, 0);
        bgemm_kernel<<<dim3(ND / 64, NG / 64), 256, 0, stream>>>(
            h0c, nullptr, WusB, bus, nullptr, spkB, ND, NC, 1);
        bgemm_kernel<<<dim3((NHD * NC) / 64, NR / 64), 256, 0, stream>>>(
            poolB, spkB, gatB, nullptr, hbuf, nullptr, NHD * NC, ND, 0);
        fin_kernel<<<NG, 256, 0, stream>>>(hbuf, att_src, att_dst, gat_b,
                                           att_W, att_b, cls_W, cls_b, mB, outp, j);
    }
}